// Round 1
// 255.684 us; speedup vs baseline: 1.2424x; 1.2424x over previous
//
#include <hip/hip_runtime.h>

#define BB 128
#define TT 512
#define CC 128

typedef short short8 __attribute__((ext_vector_type(8)));
typedef float f32x4  __attribute__((ext_vector_type(4)));
typedef unsigned u32x4 __attribute__((ext_vector_type(4)));
typedef unsigned u32x2 __attribute__((ext_vector_type(2)));

__device__ __forceinline__ unsigned pk_trunc(float a, float b) {
    // lo16 = trunc-bf16(a), hi16 = trunc-bf16(b); single v_perm
    return __builtin_amdgcn_perm(__float_as_uint(a), __float_as_uint(b), 0x03020706u);
}
__device__ __forceinline__ unsigned short f2bf(float f) {   // RNE (A setup only)
    unsigned u = __float_as_uint(f);
    u += 0x7fffu + ((u >> 16) & 1u);
    return (unsigned short)(u >> 16);
}
__device__ __forceinline__ float lo16f(unsigned u) { return __uint_as_float(u << 16); }
__device__ __forceinline__ float hi16f(unsigned u) { return __uint_as_float(u & 0xffff0000u); }

#define MFMA16(A, B, C) __builtin_amdgcn_mfma_f32_16x16x32_bf16((A), (B), (C), 0, 0, 0)

// ---------------------------------------------------------------------------
// 256 threads (4 waves) per block.
// Blocks 0..7  : scan group g. ALL FOUR waves are MFMA consumers: wave w owns
//                output tiles nt = {2w, 2w+1} (channels 32w..32w+31). State is
//                exchanged through a 2x4KB double-buffered LDS buffer
//                (column-major, XOR-swizzled -> conflict-free ds_read_b128),
//                one raw s_barrier per step (lgkmcnt(0) only; global prefetch
//                stays in flight). Each wave self-loads its E slice (exactly
//                the 2 float4 per lane its val-multiply needs) with a depth-4
//                register prefetch; exp stays in f32 (no loader waves, no ring).
// Blocks 8..135: real-path score, 4 waves x 128 rows; atomicAdd(-score).
// ---------------------------------------------------------------------------
__global__ __launch_bounds__(256, 1) void crf_all(
    const float* __restrict__ y_true, const float* __restrict__ y_pred,
    const float* __restrict__ mask, const float* __restrict__ trans,
    float* __restrict__ out)
{
    __shared__ __align__(16) unsigned sbuf[2][1024];   // 2 x 16 cols x 64 pair-words
    __shared__ float red[4][16];

    const int tid  = threadIdx.x;
    const int lane = tid & 63;
    const int w    = tid >> 6;
    const int bq   = lane & 15;
    const int q    = lane >> 4;

    if (blockIdx.x >= 8) {
        // ===================== real path (verified core, 4x128) =============
        const int rb  = blockIdx.x - 8;
        const int ts  = w * 128;
        const int te  = min(ts + 128, TT - 1);
        const float* yt_b = y_true + (size_t)rb * TT * CC;
        const float* yp_b = y_pred + (size_t)rb * TT * CC;
        const float* m_b  = mask + (size_t)rb * TT;

        float em = 0.f, tr = 0.f;
        int lprev = 0; float mprev = 0.f;
        const float* ytr = yt_b + ts * CC;
        const float* ypr = yp_b + ts * CC;
        float cyt0 = ytr[lane], cyt1 = ytr[lane + 64];
        float cyp0 = ypr[lane], cyp1 = ypr[lane + 64];
        float cm = m_b[ts];
        for (int t = ts; t <= te; ++t) {
            float nyt0 = 0.f, nyt1 = 0.f, nyp0 = 0.f, nyp1 = 0.f, nm = 0.f;
            if (t < te) {
                const float* ytn = yt_b + (t + 1) * CC;
                const float* ypn = yp_b + (t + 1) * CC;
                nyt0 = ytn[lane]; nyt1 = ytn[lane + 64];
                nyp0 = ypn[lane]; nyp1 = ypn[lane + 64];
                nm = m_b[t + 1];
            }
            unsigned long long b0 = __ballot(cyt0 > 0.5f);
            unsigned long long b1 = __ballot(cyt1 > 0.5f);
            int l = b0 ? (__ffsll(b0) - 1) : (64 + __ffsll(b1) - 1);
            float v0 = __shfl(cyp0, l & 63);
            float v1 = __shfl(cyp1, l & 63);
            float v  = (l < 64) ? v0 : v1;
            if (lane == 0) {
                if (t < ts + 128) em += cm * cm * v;
                if (t > ts)       tr += mprev * cm * trans[lprev * CC + l];
            }
            lprev = l; mprev = cm;
            cyt0 = nyt0; cyt1 = nyt1; cyp0 = nyp0; cyp1 = nyp1; cm = nm;
        }
        if (lane == 0) atomicAdd(&out[rb], -(em + tr));
        return;
    }

    // ========================== scan blocks ==========================
    const int g = blockIdx.x;
    const float* yb   = y_pred + (size_t)(g * 16 + bq) * TT * CC;
    const float* mrow = mask + (size_t)(g * 16 + bq) * TT;
    const int ch0 = 32 * w + 4 * q;          // first channel of this lane's E slice

    // Issue t=0 + t=1..4 global loads early; compute A-frags under them.
    const float4 i0 = *(const float4*)(yb + ch0);
    const float4 i1 = *(const float4*)(yb + ch0 + 16);
    const float  m0 = mrow[0];
    float4 pfa[4], pfb[4]; float pfm[4];
    #pragma unroll
    for (int p = 0; p < 4; ++p) {
        pfa[p] = *(const float4*)(yb + (size_t)(1 + p) * CC + ch0);
        pfb[p] = *(const float4*)(yb + (size_t)(1 + p) * CC + ch0 + 16);
        pfm[p] = mrow[1 + p];
    }

    // A-frags: tile nt = 2w+n2 covers output rows j = nt*16 + m (m = lane&15).
    // A[m][k] = expT[i=k][j], i = kt*32 + q*8 + e (k-layout verified by prior kernel).
    short8 Af[2][4];
    #pragma unroll
    for (int n2 = 0; n2 < 2; ++n2) {
        const int j = (2 * w + n2) * 16 + bq;
        #pragma unroll
        for (int kt = 0; kt < 4; ++kt) {
            #pragma unroll
            for (int e = 0; e < 8; ++e)
                Af[n2][kt][e] = (short)f2bf(__expf(trans[(kt * 32 + q * 8 + e) * CC + j]));
        }
    }

    // LDS state addressing: col bq at 64 words, pair P stored at word (P ^ swz),
    // swz = (bq&7)<<2.  Reads (4 x b128): exactly 8 accesses/bank (conflict-free).
    const int swz = (bq & 7) << 2;
    const int rw0 = bq * 64 + (( 0 + 4 * q) ^ swz);
    const int rw1 = bq * 64 + ((16 + 4 * q) ^ swz);
    const int rw2 = bq * 64 + ((32 + 4 * q) ^ swz);
    const int rw3 = bq * 64 + ((48 + 4 * q) ^ swz);
    const int ww0 = bq * 64 + ((16 * w + 2 * q) ^ swz);      // pairs 16w+2q, +1
    const int ww1 = bq * 64 + ((16 * w + 8 + 2 * q) ^ swz);  // pairs 16w+8+2q, +1

    // t=0 init: state = exp(y_pred[:,0,:] * m0) (live always at t=0)
    {
        unsigned p0 = pk_trunc(__expf(i0.x * m0), __expf(i0.y * m0));
        unsigned p1 = pk_trunc(__expf(i0.z * m0), __expf(i0.w * m0));
        unsigned p2 = pk_trunc(__expf(i1.x * m0), __expf(i1.y * m0));
        unsigned p3 = pk_trunc(__expf(i1.z * m0), __expf(i1.w * m0));
        u32x2 a; a[0] = p0; a[1] = p1;
        u32x2 b; b[0] = p2; b[1] = p3;
        *(u32x2*)(&sbuf[0][0] + ww0) = a;
        *(u32x2*)(&sbuf[0][0] + ww1) = b;
    }
    asm volatile("s_waitcnt lgkmcnt(0)" ::: "memory");
    __builtin_amdgcn_s_barrier();
    asm volatile("" ::: "memory");

    float lacc = 0.f;

    // One scan step. rpar = (t-1)&1 (read buffer), writes rpar^1.
    // ap: renorm step (t == 1 mod 4): pend = 1/state[0][col], lacc += log.
    // tn >= 0: prefetch E(tn) into slot p.
    auto dostep = [&](const int p, const int rpar, const bool ap, const int tn) {
        const unsigned* sb = &sbuf[rpar][0];
        unsigned* sw = &sbuf[rpar ^ 1][0];
        u32x4 B0 = *(const u32x4*)(sb + rw0);
        u32x4 B1 = *(const u32x4*)(sb + rw1);
        u32x4 B2 = *(const u32x4*)(sb + rw2);
        u32x4 B3 = *(const u32x4*)(sb + rw3);
        float pend = 1.f;
        if (ap) {
            float bc = __shfl(lo16f(B0[0]), bq, 64);   // state[0][col] from q=0 lanes
            pend = __builtin_amdgcn_rcpf(bc);
            lacc += __logf(bc);
        }
        union { u32x4 u; short8 s; } c0, c1, c2, c3;
        c0.u = B0; c1.u = B1; c2.u = B2; c3.u = B3;
        f32x4 a0 = {0.f, 0.f, 0.f, 0.f}, a1 = {0.f, 0.f, 0.f, 0.f};
        a0 = MFMA16(Af[0][0], c0.s, a0); a0 = MFMA16(Af[0][1], c1.s, a0);
        a0 = MFMA16(Af[0][2], c2.s, a0); a0 = MFMA16(Af[0][3], c3.s, a0);
        a1 = MFMA16(Af[1][0], c0.s, a1); a1 = MFMA16(Af[1][1], c1.s, a1);
        a1 = MFMA16(Af[1][2], c2.s, a1); a1 = MFMA16(Af[1][3], c3.s, a1);
        const float mm = pfm[p];
        const float4 va = pfa[p], vb = pfb[p];
        float e0 = __expf(va.x * mm), e1 = __expf(va.y * mm);
        float e2 = __expf(va.z * mm), e3 = __expf(va.w * mm);
        float f0 = __expf(vb.x * mm), f1 = __expf(vb.y * mm);
        float f2 = __expf(vb.z * mm), f3 = __expf(vb.w * mm);
        float v0 = a0[0] * e0, v1 = a0[1] * e1, v2 = a0[2] * e2, v3 = a0[3] * e3;
        float u0 = a1[0] * f0, u1 = a1[1] * f1, u2 = a1[2] * f2, u3 = a1[3] * f3;
        if (ap) {
            v0 *= pend; v1 *= pend; v2 *= pend; v3 *= pend;
            u0 *= pend; u1 *= pend; u2 *= pend; u3 *= pend;
        }
        unsigned n0 = pk_trunc(v0, v1), n1 = pk_trunc(v2, v3);
        unsigned n2 = pk_trunc(u0, u1), n3 = pk_trunc(u2, u3);
        if (__ballot(mm <= 0.f)) {              // rare keep-old (never at runtime)
            u32x2 o0 = *(const u32x2*)(sb + ww0);
            u32x2 o1 = *(const u32x2*)(sb + ww1);
            unsigned k0 = pk_trunc(lo16f(o0[0]) * pend, hi16f(o0[0]) * pend);
            unsigned k1 = pk_trunc(lo16f(o0[1]) * pend, hi16f(o0[1]) * pend);
            unsigned k2 = pk_trunc(lo16f(o1[0]) * pend, hi16f(o1[0]) * pend);
            unsigned k3 = pk_trunc(lo16f(o1[1]) * pend, hi16f(o1[1]) * pend);
            const bool kk = (mm <= 0.f);
            n0 = kk ? k0 : n0; n1 = kk ? k1 : n1;
            n2 = kk ? k2 : n2; n3 = kk ? k3 : n3;
        }
        u32x2 wv0; wv0[0] = n0; wv0[1] = n1;
        u32x2 wv1; wv1[0] = n2; wv1[1] = n3;
        *(u32x2*)(sw + ww0) = wv0;
        *(u32x2*)(sw + ww1) = wv1;
        if (tn >= 0) {                          // depth-4 E prefetch, no vmcnt drain
            pfa[p] = *(const float4*)(yb + (size_t)tn * CC + ch0);
            pfb[p] = *(const float4*)(yb + (size_t)tn * CC + ch0 + 16);
            pfm[p] = mrow[tn];
        }
        asm volatile("s_waitcnt lgkmcnt(0)" ::: "memory");   // LDS writes visible
        __builtin_amdgcn_s_barrier();                        // raw: vm stays in flight
        asm volatile("" ::: "memory");
    };

    // steps 1..508 (127 chunks of 4; tt odd -> rpar = p&1)
    for (int tt = 1; tt <= 505; tt += 4) {
        int t4 = tt + 4, t5 = tt + 5, t6 = tt + 6, t7 = tt + 7;
        if (t7 > TT - 1) t7 = TT - 1;           // only tt=505 clamps (512 -> 511)
        dostep(0, 0, true,  t4);
        dostep(1, 1, false, t5);
        dostep(2, 0, false, t6);
        dostep(3, 1, false, t7);
    }
    // steps 509 (renorm), 510
    dostep(0, 0, true,  -1);
    dostep(1, 1, false, -1);

    // -------- step 511: final sum --------
    {
        const unsigned* sb = &sbuf[0][0];       // (511-1)&1 == 0
        u32x4 B0 = *(const u32x4*)(sb + rw0);
        u32x4 B1 = *(const u32x4*)(sb + rw1);
        u32x4 B2 = *(const u32x4*)(sb + rw2);
        u32x4 B3 = *(const u32x4*)(sb + rw3);
        union { u32x4 u; short8 s; } c0, c1, c2, c3;
        c0.u = B0; c1.u = B1; c2.u = B2; c3.u = B3;
        f32x4 a0 = {0.f, 0.f, 0.f, 0.f}, a1 = {0.f, 0.f, 0.f, 0.f};
        a0 = MFMA16(Af[0][0], c0.s, a0); a0 = MFMA16(Af[0][1], c1.s, a0);
        a0 = MFMA16(Af[0][2], c2.s, a0); a0 = MFMA16(Af[0][3], c3.s, a0);
        a1 = MFMA16(Af[1][0], c0.s, a1); a1 = MFMA16(Af[1][1], c1.s, a1);
        a1 = MFMA16(Af[1][2], c2.s, a1); a1 = MFMA16(Af[1][3], c3.s, a1);
        const float mm = pfm[2];
        const float4 va = pfa[2], vb = pfb[2];
        float e0 = __expf(va.x * mm), e1 = __expf(va.y * mm);
        float e2 = __expf(va.z * mm), e3 = __expf(va.w * mm);
        float f0 = __expf(vb.x * mm), f1 = __expf(vb.y * mm);
        float f2 = __expf(vb.z * mm), f3 = __expf(vb.w * mm);
        float ssum = a0[0] * e0 + a0[1] * e1 + a0[2] * e2 + a0[3] * e3
                   + a1[0] * f0 + a1[1] * f1 + a1[2] * f2 + a1[3] * f3;
        if (__ballot(mm <= 0.f)) {              // pend == 1 here (511 % 4 == 3)
            u32x2 o0 = *(const u32x2*)(sb + ww0);
            u32x2 o1 = *(const u32x2*)(sb + ww1);
            float os = lo16f(o0[0]) + hi16f(o0[0]) + lo16f(o0[1]) + hi16f(o0[1])
                     + lo16f(o1[0]) + hi16f(o1[0]) + lo16f(o1[1]) + hi16f(o1[1]);
            ssum = (mm <= 0.f) ? os : ssum;
        }
        ssum += __shfl_xor(ssum, 16, 64);
        ssum += __shfl_xor(ssum, 32, 64);
        if (lane < 16) red[w][lane] = ssum;
        asm volatile("s_waitcnt lgkmcnt(0)" ::: "memory");
        __builtin_amdgcn_s_barrier();
        asm volatile("" ::: "memory");
        if (w == 0 && lane < 16) {
            float tot = red[0][lane] + red[1][lane] + red[2][lane] + red[3][lane];
            atomicAdd(&out[g * 16 + lane], __logf(tot) + lacc);
        }
    }
}

// ---------------------------------------------------------------------------
extern "C" void kernel_launch(void* const* d_in, const int* in_sizes, int n_in,
                              void* d_out, int out_size, void* d_ws, size_t ws_size,
                              hipStream_t stream) {
    (void)in_sizes; (void)n_in; (void)out_size; (void)d_ws; (void)ws_size;
    const float* y_true = (const float*)d_in[0];
    const float* y_pred = (const float*)d_in[1];
    const float* mask   = (const float*)d_in[2];
    const float* trans  = (const float*)d_in[3];
    float* out = (float*)d_out;

    hipMemsetAsync(out, 0, BB * sizeof(float), stream);
    crf_all<<<dim3(8 + BB), 256, 0, stream>>>(y_true, y_pred, mask, trans, out);
}